// Round 12
// baseline (174.475 us; speedup 1.0000x reference)
//
#include <hip/hip_runtime.h>
#include <math.h>

// B=2, S=2048, D=1024, H=16, DK=64, rope_dim=32, causal MHA. fp32 in/out.
// convert->bf16 | QKV MFMA-GEMM dbuf BM=128/BN=64, grid 1536 = 6 blocks/CU
// (+fast RoPE; V^T via block-level LDS transpose, 256-B stores) |
// exclusive-ownership MFMA flash (r8: 512 blocks LPT-paired, zero atomics,
// in-kernel normalize) | out GEMM BM=64/BN=64, grid 1024 = 4 blocks/CU.

static constexpr int Bb  = 2;
static constexpr int Ss  = 2048;
static constexpr int Hh  = 16;
static constexpr int DKk = 64;

static constexpr size_t QSZ = (size_t)Bb * Hh * Ss * DKk;   // 4,194,304

// ws bytes: Wo[0,2M) | x[2M,10M) | Wqkv[10M,16M) | Q[18M,26M) | K[26M,34M) |
//           Vt[34M,42M) | Ob[42M,50M).
static constexpr size_t WOB_E  = 0;
static constexpr size_t XB_E   = 1048576;
static constexpr size_t WQKV_E = 5242880;
static constexpr size_t QB_E   = 9437184;
static constexpr size_t OB_E   = QB_E + 3*QSZ;

typedef __attribute__((ext_vector_type(8))) short short8;
typedef __attribute__((ext_vector_type(4))) float f32x4;

__device__ __forceinline__ unsigned short f2bf(float f) {   // RNE
    unsigned int u = __float_as_uint(f);
    u += 0x7fffu + ((u >> 16) & 1u);
    return (unsigned short)(u >> 16);
}

// packed bf16x2 via HW cvt_pk (RNE): 1 VALU op vs 3+ for bit-munged pack.
__device__ __forceinline__ unsigned int cvtpk_bf16(float lo, float hi) {
    unsigned int r;
    asm("v_cvt_pk_bf16_f32 %0, %1, %2" : "=v"(r) : "v"(lo), "v"(hi));
    return r;
}

__device__ __forceinline__ float fexp2(float x) {           // 2^x, exp2(-inf)=0
    float r;
    asm("v_exp_f32 %0, %1" : "=v"(r) : "v"(x));
    return r;
}

__device__ __forceinline__ float fsin_rev(float r) {        // sin(2*pi*r)
    float o;
    asm("v_sin_f32 %0, %1" : "=v"(o) : "v"(r));
    return o;
}
__device__ __forceinline__ float fcos_rev(float r) {
    float o;
    asm("v_cos_f32 %0, %1" : "=v"(o) : "v"(r));
    return o;
}

__device__ __forceinline__ void gl16(const unsigned short* g, unsigned short* l) {
    __builtin_amdgcn_global_load_lds(
        (const __attribute__((address_space(1))) void*)g,
        (__attribute__((address_space(3))) void*)l, 16, 0, 0);
}

// ---------------------------------------------------------------------------
// fp32->bf16 of Wo | x | Wqkv into ws.
// ---------------------------------------------------------------------------
__global__ __launch_bounds__(256)
void convert_bf16(const float* __restrict__ x, const float* __restrict__ wqkv,
                  const float* __restrict__ wo, unsigned short* __restrict__ dst)
{
    const size_t i4 = ((size_t)blockIdx.x * 256 + threadIdx.x) * 4;
    const float* src;
    if (i4 < 1048576)      src = wo   + i4;
    else if (i4 < 5242880) src = x    + (i4 - 1048576);
    else                   src = wqkv + (i4 - 5242880);
    const float4 v = *(const float4*)src;
    ushort4 p = { f2bf(v.x), f2bf(v.y), f2bf(v.z), f2bf(v.w) };
    *(ushort4*)(dst + i4) = p;
}

// ---------------------------------------------------------------------------
// bf16 MFMA GEMM, dbuf in a flat LDS pool. C = A[M,K] * B[N,K]^T, K=1024,
// BK=32. 4 waves, wave w owns rows [w*BM/4, (w+1)*BM/4) x all BN cols.
// MODE 0: C fp32. MODE 1 (BM=128, BN=64: block = one (q,h)): QKV scatter +
// fused RoPE; V^T via block-level 64x128 LDS transpose, 256-B stores.
// Smaller tiles trade per-wave work for co-residency: QKV 6 blocks/CU,
// out 4 blocks/CU (2-phase loop is latency-bound; waves hide the drain).
// ---------------------------------------------------------------------------
template<int MODE, int BM, int BN>
__global__ __launch_bounds__(256)
void gemm_mfma(const unsigned short* __restrict__ A,
               const unsigned short* __restrict__ Bm,
               float* __restrict__ C, unsigned short* __restrict__ QKV, int N)
{
    constexpr int K   = 1024;
    constexpr int MF  = BM / 64;        // m-frags per wave (wave rows = BM/4)
    constexpr int NFr = BN / 16;        // n-frags per wave (full BN width)
    constexpr int ASZ = BM * 32;
    constexpr int BSZ = BN * 32;
    __shared__ unsigned short ShPool[2*ASZ + 2*BSZ];
    unsigned short* As0 = ShPool;
    unsigned short* As1 = ShPool + ASZ;
    unsigned short* Bs0 = ShPool + 2*ASZ;
    unsigned short* Bs1 = ShPool + 2*ASZ + BSZ;

    const int t    = threadIdx.x;
    const int lane = t & 63;
    const int w    = t >> 6;
    const int l15  = lane & 15;
    const int quad = lane >> 4;
    const int n0   = blockIdx.x * BN;
    const int m0   = blockIdx.y * BM;

    const unsigned short* Ag = A  + (size_t)(m0 + (t >> 2)) * K + (t & 3) * 8;
    const unsigned short* Bg = Bm + (size_t)(n0 + (t >> 2)) * K + (t & 3) * 8;

    f32x4 acc[MF][NFr];
    #pragma unroll
    for (int i = 0; i < MF; i++)
        #pragma unroll
        for (int j = 0; j < NFr; j++) acc[i][j] = f32x4{0.f, 0.f, 0.f, 0.f};

    auto stage = [&](int k0, unsigned short* Asb, unsigned short* Bsb) {
        #pragma unroll
        for (int rr = 0; rr < BM/64; rr++)
            gl16(Ag + (size_t)rr*64*K + k0, Asb + rr*2048 + t*8);
        #pragma unroll
        for (int rr = 0; rr < BN/64; rr++)
            gl16(Bg + (size_t)rr*64*K + k0, Bsb + rr*2048 + t*8);
    };
    auto comp = [&](const unsigned short* Asb, const unsigned short* Bsb) {
        short8 af[MF], bfv[NFr];
        #pragma unroll
        for (int mf = 0; mf < MF; mf++)
            af[mf] = *(const short8*)&Asb[(w*(BM/4) + mf*16 + l15) * 32 + quad*8];
        #pragma unroll
        for (int nf = 0; nf < NFr; nf++)
            bfv[nf] = *(const short8*)&Bsb[(nf*16 + l15) * 32 + quad*8];
        #pragma unroll
        for (int mf = 0; mf < MF; mf++)
            #pragma unroll
            for (int nf = 0; nf < NFr; nf++)
                acc[mf][nf] = __builtin_amdgcn_mfma_f32_16x16x32_bf16(
                    af[mf], bfv[nf], acc[mf][nf], 0, 0, 0);
    };

    stage(0, As0, Bs0);
    for (int k0 = 0; k0 < K; k0 += 64) {
        __syncthreads();
        stage(k0 + 32, As1, Bs1);
        comp(As0, Bs0);
        __syncthreads();
        if (k0 + 64 < K) stage(k0 + 64, As0, Bs0);
        comp(As1, Bs1);
    }

    if (MODE == 0) {
        #pragma unroll
        for (int mf = 0; mf < MF; mf++)
            #pragma unroll
            for (int r = 0; r < 4; r++) {
                float* crow = C + (size_t)(m0 + w*(BM/4) + mf*16 + quad*4 + r) * N
                            + n0;
                #pragma unroll
                for (int nf = 0; nf < NFr; nf++)
                    crow[nf*16 + l15] = acc[mf][nf][r];
            }
    } else {
        __syncthreads();                       // staging pool dead -> reusable
        const int q  = n0 >> 10;               // block-uniform (BN=64)
        const int h  = (n0 >> 6) & 15;
        const int b  = m0 >> 11;
        const int s0 = m0 & 2047;
        if (q == 2) {
            // Block holds the full 128(s) x 64(d) V tile. Transpose via a
            // 64x128 LDS region (16 KB <= pool): write XOR-swizzled frags,
            // barrier, then store Vt rows as 256-B contiguous segments.
            #pragma unroll
            for (int mf = 0; mf < MF; mf++)
                #pragma unroll
                for (int nf = 0; nf < NFr; nf++) {
                    const int d  = nf*16 + l15;
                    const int sl = w*(BM/4) + mf*16 + quad*4;
                    ushort4 pv = { f2bf(acc[mf][nf][0]), f2bf(acc[mf][nf][1]),
                                   f2bf(acc[mf][nf][2]), f2bf(acc[mf][nf][3]) };
                    *(ushort4*)((char*)ShPool
                        + d*256 + ((sl*2) ^ ((d & 15) << 4))) = pv;
                }
            __syncthreads();
            unsigned short* vb = QKV + 2*QSZ
                               + (size_t)(b*Hh + h) * DKk * Ss + s0;
            #pragma unroll
            for (int p = 0; p < 8; p++) {
                const int d  = p*8 + (t >> 5);             // 0..63
                const int s4 = (t & 31) * 4;               // 0..124
                const ushort4 pv = *(const ushort4*)((char*)ShPool
                    + d*256 + ((s4*2) ^ ((d & 15) << 4)));
                *(ushort4*)(vb + (size_t)d * Ss + s4) = pv;
            }
        } else {
            // Q scale folds 1/sqrt(64) and log2(e) for flash's exp2 softmax
            const float qsc = (q == 0) ? 0.125f * 1.44269504088896f : 1.0f;
            const float rev_freq = (float)(exp(-(double)(2 * l15) / 32.0
                                   * log(6000.0)) / 6.283185307179586);
            unsigned short* base = QKV + (size_t)q * QSZ
                                 + ((size_t)(b*Hh + h) * Ss) * DKk;
            #pragma unroll
            for (int mf = 0; mf < MF; mf++)
                #pragma unroll
                for (int r = 0; r < 4; r++) {
                    const int s = s0 + w*(BM/4) + mf*16 + quad*4 + r;
                    float rev = (float)s * rev_freq;
                    rev -= floorf(rev);
                    const float sn = fsin_rev(rev);
                    const float cs = fcos_rev(rev);
                    const float v0 = acc[mf][0][r] * qsc;
                    const float v1 = acc[mf][1][r] * qsc;
                    unsigned short* rowp = base + (size_t)s * DKk;
                    rowp[l15]      = f2bf(v0 * cs - v1 * sn);
                    rowp[16 + l15] = f2bf(v1 * cs + v0 * sn);
                    rowp[32 + l15] = f2bf(acc[mf][2][r] * qsc);
                    rowp[48 + l15] = f2bf(acc[mf][3][r] * qsc);
                }
        }
    }
}

// ---------------------------------------------------------------------------
// Exclusive-ownership MFMA causal flash, LPT-paired. 512 blocks, one q-tile
// (128 rows) each: xcd = bid&7 owns bh [4x,4x+4); slot = bid>>3 in [0,64):
// slots 0-31 heavy (QT = 15-(slot&7)), slots 32-63 light (QT = slot&7),
// same bh for slot s and s+32. Round-robin dispatch puts bid c and c+256 on
// the same CU -> every CU gets 34 items across 2 blocks (8 waves/CU), both
// streaming the same head's K/V. Zero atomics: full key range local ->
// normalize in-kernel, store bf16 Ob. 2-buffer LDS dbuf + __syncthreads.
// S computed TRANSPOSED (A=K, B=Q); sigma-permuted PV; cvt_pk P-pack.
// ---------------------------------------------------------------------------
__global__ __launch_bounds__(256)
void flash_mfma(const unsigned short* __restrict__ Qa,
                const unsigned short* __restrict__ Ka,
                const unsigned short* __restrict__ Va,
                unsigned short* __restrict__ Ob)
{
    __shared__ unsigned short Ks0[64*64];
    __shared__ unsigned short Ks1[64*64];
    __shared__ unsigned short Vs0[64*64];
    __shared__ unsigned short Vs1[64*64];

    const int t    = threadIdx.x;
    const int lane = t & 63;
    const int w    = t >> 6;
    const int l15  = lane & 15;
    const int quad = lane >> 4;

    const int bid   = blockIdx.x;         // 0..511
    const int xcd   = bid & 7;
    const int slot  = bid >> 3;           // 0..63
    const bool hv   = slot < 32;
    const int sub   = hv ? slot : slot - 32;
    const int bh    = xcd*4 + (sub >> 3);
    const int j     = sub & 7;
    const int QT    = hv ? 15 - j : j;
    const int n     = 2*QT + 2;           // k-tiles for this q-tile

    const int c0 = t,       r0 = c0 >> 3, g0 = ((c0 & 7) ^ (r0 & 7)) * 8;
    const int c1 = t + 256, r1 = c1 >> 3, g1 = ((c1 & 7) ^ (r1 & 7)) * 8;

    auto stage = [&](int skt, unsigned short* Ksb, unsigned short* Vsb) {
        const unsigned short* Kg = Ka + (size_t)bh * Ss * DKk + (size_t)skt*64*DKk;
        const unsigned short* Vg = Va + (size_t)bh * DKk * Ss + skt*64;
        gl16(Kg + (size_t)r0*DKk + g0, Ksb + t*8);
        gl16(Kg + (size_t)r1*DKk + g1, Ksb + (t+256)*8);
        gl16(Vg + (size_t)r0*Ss  + g0, Vsb + t*8);
        gl16(Vg + (size_t)r1*Ss  + g1, Vsb + (t+256)*8);
    };

    short8 qf[2][2];          // [mfq][kc]  B-frags of Q
    f32x4 o[2][4];            // [mfq][dt]  O C-frags
    float lacc[2];            // row-sum partial (this quad's keys)
    #pragma unroll
    for (int mfq = 0; mfq < 2; mfq++) {
        lacc[mfq] = 0.f;
        #pragma unroll
        for (int i = 0; i < 4; i++) o[mfq][i] = f32x4{0.f,0.f,0.f,0.f};
    }
    #pragma unroll
    for (int mfq = 0; mfq < 2; mfq++) {
        const unsigned short* qrow = Qa + (size_t)bh * Ss * DKk
            + (size_t)(QT*128 + w*32 + mfq*16 + l15) * DKk;
        qf[mfq][0] = *(const short8*)(qrow + quad*8);
        qf[mfq][1] = *(const short8*)(qrow + 32 + quad*8);
    }

    auto compute = [&](const unsigned short* Ksb, const unsigned short* Vsb,
                       int ckt) {
        // S^T = K Q^T : D[m=key nt*16+4quad+r][n=q w*32+mfq*16+l15]
        f32x4 sc[4][2];
        #pragma unroll
        for (int nt = 0; nt < 4; nt++)
            #pragma unroll
            for (int mfq = 0; mfq < 2; mfq++) sc[nt][mfq] = f32x4{0.f,0.f,0.f,0.f};
        #pragma unroll
        for (int nt = 0; nt < 4; nt++)
            #pragma unroll
            for (int kc = 0; kc < 2; kc++) {
                const short8 kf = *(const short8*)&Ksb[(nt*16 + l15)*64
                                   + (((kc*4 + quad) ^ (l15 & 7)) * 8)];
                sc[nt][0] = __builtin_amdgcn_mfma_f32_16x16x32_bf16(kf, qf[0][kc], sc[nt][0], 0,0,0);
                sc[nt][1] = __builtin_amdgcn_mfma_f32_16x16x32_bf16(kf, qf[1][kc], sc[nt][1], 0,0,0);
            }

        if (ckt >= 2*QT) {                      // diagonal tiles only
            const int kb = ckt*64 + quad*4;
            const int qb = QT*128 + w*32 + l15;
            #pragma unroll
            for (int nt = 0; nt < 4; nt++)
                #pragma unroll
                for (int mfq = 0; mfq < 2; mfq++)
                    #pragma unroll
                    for (int r = 0; r < 4; r++)
                        if (kb + nt*16 + r > qb + mfq*16)
                            sc[nt][mfq][r] = -INFINITY;
        }

        #pragma unroll
        for (int nt = 0; nt < 4; nt++)
            #pragma unroll
            for (int mfq = 0; mfq < 2; mfq++)
                #pragma unroll
                for (int r = 0; r < 4; r++)
                    sc[nt][mfq][r] = fexp2(sc[nt][mfq][r]);
        #pragma unroll
        for (int mfq = 0; mfq < 2; mfq++)
            #pragma unroll
            for (int nt = 0; nt < 4; nt++)
                lacc[mfq] += (sc[nt][mfq][0] + sc[nt][mfq][1])
                           + (sc[nt][mfq][2] + sc[nt][mfq][3]);

        // P A-frags via sigma: frag (mfq,kc) word v packs
        // sc[2kc+(v>>1)][mfq][2(v&1)] (lo), sc[2kc+(v>>1)][mfq][2(v&1)+1] (hi)
        short8 pfrag[2][2];                    // [mfq][kc]
        #pragma unroll
        for (int mfq = 0; mfq < 2; mfq++)
            #pragma unroll
            for (int kc = 0; kc < 2; kc++) {
                unsigned int pk[4];
                #pragma unroll
                for (int v = 0; v < 4; v++) {
                    const int nt = 2*kc + (v >> 1);
                    const int rr = 2*(v & 1);
                    pk[v] = cvtpk_bf16(sc[nt][mfq][rr], sc[nt][mfq][rr+1]);
                }
                pfrag[mfq][kc] = *(short8*)&pk[0];
            }

        // O += P V with sigma-permuted V B-frags (two b64 reads each)
        #pragma unroll
        for (int dt = 0; dt < 4; dt++) {
            const int row = dt*16 + l15;       // d row of Vt tile
            const int rx  = row & 7;
            const int wi  = 4*(quad & 1);
            #pragma unroll
            for (int kc = 0; kc < 2; kc++) {
                const ushort4 lo = *(const ushort4*)&Vsb[row*64
                                    + (((4*kc + (quad>>1)) ^ rx) * 8) + wi];
                const ushort4 hi = *(const ushort4*)&Vsb[row*64
                                    + (((4*kc + 2 + (quad>>1)) ^ rx) * 8) + wi];
                short8 vf;
                vf[0]=lo.x; vf[1]=lo.y; vf[2]=lo.z; vf[3]=lo.w;
                vf[4]=hi.x; vf[5]=hi.y; vf[6]=hi.z; vf[7]=hi.w;
                o[0][dt] = __builtin_amdgcn_mfma_f32_16x16x32_bf16(
                    pfrag[0][kc], vf, o[0][dt], 0,0,0);
                o[1][dt] = __builtin_amdgcn_mfma_f32_16x16x32_bf16(
                    pfrag[1][kc], vf, o[1][dt], 0,0,0);
            }
        }
    };

    stage(0, Ks0, Vs0);
    int i = 0;
    while (true) {
        __syncthreads();
        const bool h1 = (i + 1 < n);
        if (h1) stage(i + 1, Ks1, Vs1);
        compute(Ks0, Vs0, i);
        if (!h1) break;
        i++;
        __syncthreads();
        const bool h2 = (i + 1 < n);
        if (h2) stage(i + 1, Ks0, Vs0);
        compute(Ks1, Vs1, i);
        if (!h2) break;
        i++;
    }

    // Normalize and store bf16 (full key range was local to this block).
    {
        const int b = bh >> 4, h = bh & 15;
        const int q0 = QT*128 + w*32;
        #pragma unroll
        for (int mfq = 0; mfq < 2; mfq++) {
            float ls = lacc[mfq];
            ls += __shfl_xor(ls, 16);      // sum the 4 quads' key partials
            ls += __shfl_xor(ls, 32);      // -> every lane: denom for q-col l15
            #pragma unroll
            for (int r = 0; r < 4; r++) {
                const int x = quad*4 + r;  // q-row index within 16-block
                const float inv = 1.0f / __shfl(ls, (lane & 48) + x);
                const int row = q0 + mfq*16 + x;
                unsigned short* orow = Ob + ((size_t)b*Ss + row) * 1024 + h*64;
                #pragma unroll
                for (int dt = 0; dt < 4; dt++)
                    orow[dt*16 + l15] = f2bf(o[mfq][dt][r] * inv);
            }
        }
    }
}

// ---------------------------------------------------------------------------
extern "C" void kernel_launch(void* const* d_in, const int* in_sizes, int n_in,
                              void* d_out, int out_size, void* d_ws, size_t ws_size,
                              hipStream_t stream)
{
    const float* x    = (const float*)d_in[0];
    const float* Wqkv = (const float*)d_in[1];
    const float* Wo   = (const float*)d_in[2];
    float* out = (float*)d_out;
    unsigned short* wsu = (unsigned short*)d_ws;

    const dim3 blk(256);
    convert_bf16<<<dim3(8192), blk, 0, stream>>>(x, Wqkv, Wo, wsu);
    gemm_mfma<1,128,64><<<dim3(48, 32), blk, 0, stream>>>(wsu + XB_E,
                                    wsu + WQKV_E, nullptr, wsu + QB_E, 3072);
    flash_mfma<<<dim3(512), blk, 0, stream>>>(wsu + QB_E, wsu + QB_E + QSZ,
                                              wsu + QB_E + 2*QSZ, wsu + OB_E);
    gemm_mfma<0,64,64><<<dim3(16, 64), blk, 0, stream>>>(wsu + OB_E,
                                    wsu + WOB_E, out, nullptr, 1024);
}

// Round 13
// 170.779 us; speedup vs baseline: 1.0216x; 1.0216x over previous
//
#include <hip/hip_runtime.h>
#include <math.h>

// B=2, S=2048, D=1024, H=16, DK=64, rope_dim=32, causal MHA. fp32 in/out.
// convert->bf16 | QKV MFMA-GEMM dbuf (+fast RoPE; V^T via LDS transpose) |
// exclusive-ownership MFMA flash, 512 blocks (1 q-tile each), LPT-paired by
// dispatch order so each CU gets a heavy+light pair (34 items, 8 waves/CU),
// zero atomics, in-kernel normalize -> bf16 Ob | out GEMM. 4 dispatches.
// Locked config (r11 best, 171.0 us): no setprio (r10: -2.9), KVBLK=64
// (r9: 128 regressed), BN=128 QKV tile (r12: BN=64 regressed), no
// launch_bounds forcing (r4: VGPR collapse).

static constexpr int Bb  = 2;
static constexpr int Ss  = 2048;
static constexpr int Hh  = 16;
static constexpr int DKk = 64;

static constexpr size_t QSZ = (size_t)Bb * Hh * Ss * DKk;   // 4,194,304

// ws bytes: Wo[0,2M) | x[2M,10M) | Wqkv[10M,16M) | Q[18M,26M) | K[26M,34M) |
//           Vt[34M,42M) | Ob[42M,50M).
static constexpr size_t WOB_E  = 0;
static constexpr size_t XB_E   = 1048576;
static constexpr size_t WQKV_E = 5242880;
static constexpr size_t QB_E   = 9437184;
static constexpr size_t OB_E   = QB_E + 3*QSZ;

typedef __attribute__((ext_vector_type(8))) short short8;
typedef __attribute__((ext_vector_type(4))) float f32x4;

__device__ __forceinline__ unsigned short f2bf(float f) {   // RNE
    unsigned int u = __float_as_uint(f);
    u += 0x7fffu + ((u >> 16) & 1u);
    return (unsigned short)(u >> 16);
}

// packed bf16x2 via HW cvt_pk (RNE): 1 VALU op vs 3+ for bit-munged pack.
__device__ __forceinline__ unsigned int cvtpk_bf16(float lo, float hi) {
    unsigned int r;
    asm("v_cvt_pk_bf16_f32 %0, %1, %2" : "=v"(r) : "v"(lo), "v"(hi));
    return r;
}

__device__ __forceinline__ float fexp2(float x) {           // 2^x, exp2(-inf)=0
    float r;
    asm("v_exp_f32 %0, %1" : "=v"(r) : "v"(x));
    return r;
}

__device__ __forceinline__ float fsin_rev(float r) {        // sin(2*pi*r)
    float o;
    asm("v_sin_f32 %0, %1" : "=v"(o) : "v"(r));
    return o;
}
__device__ __forceinline__ float fcos_rev(float r) {
    float o;
    asm("v_cos_f32 %0, %1" : "=v"(o) : "v"(r));
    return o;
}

__device__ __forceinline__ void gl16(const unsigned short* g, unsigned short* l) {
    __builtin_amdgcn_global_load_lds(
        (const __attribute__((address_space(1))) void*)g,
        (__attribute__((address_space(3))) void*)l, 16, 0, 0);
}

// ---------------------------------------------------------------------------
// fp32->bf16 of Wo | x | Wqkv into ws.
// ---------------------------------------------------------------------------
__global__ __launch_bounds__(256)
void convert_bf16(const float* __restrict__ x, const float* __restrict__ wqkv,
                  const float* __restrict__ wo, unsigned short* __restrict__ dst)
{
    const size_t i4 = ((size_t)blockIdx.x * 256 + threadIdx.x) * 4;
    const float* src;
    if (i4 < 1048576)      src = wo   + i4;
    else if (i4 < 5242880) src = x    + (i4 - 1048576);
    else                   src = wqkv + (i4 - 5242880);
    const float4 v = *(const float4*)src;
    ushort4 p = { f2bf(v.x), f2bf(v.y), f2bf(v.z), f2bf(v.w) };
    *(ushort4*)(dst + i4) = p;
}

// ---------------------------------------------------------------------------
// bf16 MFMA GEMM, dbuf in a flat LDS pool. C = A[M,K] * B[N,K]^T,
// K=1024, BK=32, BM=128, BN=128|64.  MODE 0: C fp32.  MODE 1: QKV scatter
// + fused RoPE (HW v_sin/v_cos); V^T written via per-wave LDS transpose
// (XOR-swizzled 4 KB chunk) as 128-B contiguous segments.
// ---------------------------------------------------------------------------
template<int MODE, int BN>
__global__ __launch_bounds__(256)
void gemm_mfma(const unsigned short* __restrict__ A,
               const unsigned short* __restrict__ Bm,
               float* __restrict__ C, unsigned short* __restrict__ QKV, int N)
{
    constexpr int K   = 1024;
    constexpr int NF  = BN / 32;
    constexpr int ASZ = 128 * 32;
    constexpr int BSZ = BN * 32;
    __shared__ unsigned short ShPool[2 * ASZ + 2 * BSZ];
    unsigned short* As0 = ShPool;
    unsigned short* As1 = ShPool + ASZ;
    unsigned short* Bs0 = ShPool + 2 * ASZ;
    unsigned short* Bs1 = ShPool + 2 * ASZ + BSZ;

    const int t    = threadIdx.x;
    const int lane = t & 63;
    const int w    = t >> 6;
    const int l15  = lane & 15;
    const int quad = lane >> 4;
    const int wr   = w >> 1;
    const int wc   = w & 1;
    const int n0   = blockIdx.x * BN;
    const int m0   = blockIdx.y * 128;

    const unsigned short* Ag = A  + (size_t)(m0 + (t >> 2)) * K + (t & 3) * 8;
    const unsigned short* Bg = Bm + (size_t)(n0 + (t >> 2)) * K + (t & 3) * 8;

    f32x4 acc[4][NF];
    #pragma unroll
    for (int i = 0; i < 4; i++)
        #pragma unroll
        for (int j = 0; j < NF; j++) acc[i][j] = f32x4{0.f, 0.f, 0.f, 0.f};

    auto stage = [&](int k0, unsigned short* Asb, unsigned short* Bsb) {
        gl16(Ag + k0,        Asb + t*8);
        gl16(Ag + 64*K + k0, Asb + 2048 + t*8);
        gl16(Bg + k0,        Bsb + t*8);
        if (BN == 128) gl16(Bg + 64*K + k0, Bsb + 2048 + t*8);
    };
    auto comp = [&](const unsigned short* Asb, const unsigned short* Bsb) {
        short8 af[4], bfv[NF];
        #pragma unroll
        for (int mf = 0; mf < 4; mf++)
            af[mf] = *(const short8*)&Asb[(wr*64 + mf*16 + l15) * 32 + quad*8];
        #pragma unroll
        for (int nf = 0; nf < NF; nf++)
            bfv[nf] = *(const short8*)&Bsb[(wc*(BN/2) + nf*16 + l15) * 32 + quad*8];
        #pragma unroll
        for (int mf = 0; mf < 4; mf++)
            #pragma unroll
            for (int nf = 0; nf < NF; nf++)
                acc[mf][nf] = __builtin_amdgcn_mfma_f32_16x16x32_bf16(
                    af[mf], bfv[nf], acc[mf][nf], 0, 0, 0);
    };

    stage(0, As0, Bs0);
    for (int k0 = 0; k0 < K; k0 += 64) {
        __syncthreads();
        stage(k0 + 32, As1, Bs1);
        comp(As0, Bs0);
        __syncthreads();
        if (k0 + 64 < K) stage(k0 + 64, As0, Bs0);
        comp(As1, Bs1);
    }

    if (MODE == 0) {
        #pragma unroll
        for (int mf = 0; mf < 4; mf++)
            #pragma unroll
            for (int r = 0; r < 4; r++) {
                float* crow = C + (size_t)(m0 + wr*64 + mf*16 + quad*4 + r) * N
                            + n0 + wc*(BN/2);
                #pragma unroll
                for (int nf = 0; nf < NF; nf++)
                    crow[nf*16 + l15] = acc[mf][nf][r];
            }
    } else {
        __syncthreads();                       // staging pool dead -> reusable
        const int col0 = n0 + wc*64;           // wave-uniform (BN=128)
        const int q    = col0 >> 10;
        const int h    = (col0 >> 6) & 15;
        const int row0 = m0 + wr*64;
        const int b    = row0 >> 11;
        const int s0   = row0 & 2047;
        if (q == 2) {
            // Wave holds the full 64x64 (s x d) V tile. Transpose via
            // wave-private 4 KB LDS chunk (byte ^= (d&7)<<4 swizzle) then
            // store Vt rows as 128-B contiguous segments.
            unsigned short* chunk = ShPool + w * 2048;     // 4 KB per wave
            unsigned short* vb = QKV + 2*QSZ
                               + (size_t)(b*Hh + h) * DKk * Ss + s0;
            #pragma unroll
            for (int pass = 0; pass < 2; pass++) {
                #pragma unroll
                for (int mf = 0; mf < 4; mf++)
                    #pragma unroll
                    for (int nfp = 0; nfp < 2; nfp++) {
                        const int nf = pass*2 + nfp;
                        const int dl = nfp*16 + l15;
                        const int sby = (mf*16 + quad*4) * 2;
                        ushort4 pv = { f2bf(acc[mf][nf][0]), f2bf(acc[mf][nf][1]),
                                       f2bf(acc[mf][nf][2]), f2bf(acc[mf][nf][3]) };
                        *(ushort4*)((char*)chunk
                            + dl*128 + (sby ^ ((dl & 7) << 4))) = pv;
                    }
                // same-wave LDS ops are in-order; no barrier needed
                #pragma unroll
                for (int dblk = 0; dblk < 8; dblk++) {
                    const int dl = dblk*4 + quad;          // 0..31
                    const int sl = l15*4;                  // s within tile
                    const ushort4 pv = *(const ushort4*)((char*)chunk
                        + dl*128 + ((sl*2) ^ ((dl & 7) << 4)));
                    *(ushort4*)(vb + (size_t)(pass*32 + dl) * Ss + sl) = pv;
                }
            }
        } else {
            // Q scale folds 1/sqrt(64) and log2(e) for flash's exp2 softmax
            const float qsc = (q == 0) ? 0.125f * 1.44269504088896f : 1.0f;
            const float rev_freq = (float)(exp(-(double)(2 * l15) / 32.0
                                   * log(6000.0)) / 6.283185307179586);
            unsigned short* base = QKV + (size_t)q * QSZ
                                 + ((size_t)(b*Hh + h) * Ss) * DKk;
            #pragma unroll
            for (int mf = 0; mf < 4; mf++)
                #pragma unroll
                for (int r = 0; r < 4; r++) {
                    const int s = s0 + mf*16 + quad*4 + r;
                    float rev = (float)s * rev_freq;
                    rev -= floorf(rev);
                    const float sn = fsin_rev(rev);
                    const float cs = fcos_rev(rev);
                    const float v0 = acc[mf][0][r] * qsc;
                    const float v1 = acc[mf][1][r] * qsc;
                    unsigned short* rowp = base + (size_t)s * DKk;
                    rowp[l15]      = f2bf(v0 * cs - v1 * sn);
                    rowp[16 + l15] = f2bf(v1 * cs + v0 * sn);
                    rowp[32 + l15] = f2bf(acc[mf][2][r] * qsc);
                    rowp[48 + l15] = f2bf(acc[mf][3][r] * qsc);
                }
        }
    }
}

// ---------------------------------------------------------------------------
// Exclusive-ownership MFMA causal flash, LPT-paired. 512 blocks, one q-tile
// (128 rows) each: xcd = bid&7 owns bh [4x,4x+4); slot = bid>>3 in [0,64):
// slots 0-31 heavy (QT = 15-(slot&7)), slots 32-63 light (QT = slot&7),
// same bh for slot s and s+32. Round-robin dispatch puts bid c and c+256 on
// the same CU -> every CU gets 34 items across 2 blocks (8 waves/CU), both
// streaming the same head's K/V. Zero atomics: full key range local ->
// normalize in-kernel, store bf16 Ob. 2-buffer LDS dbuf + __syncthreads.
// S computed TRANSPOSED (A=K, B=Q); sigma-permuted PV; cvt_pk P-pack.
// ---------------------------------------------------------------------------
__global__ __launch_bounds__(256)
void flash_mfma(const unsigned short* __restrict__ Qa,
                const unsigned short* __restrict__ Ka,
                const unsigned short* __restrict__ Va,
                unsigned short* __restrict__ Ob)
{
    __shared__ unsigned short Ks0[64*64];
    __shared__ unsigned short Ks1[64*64];
    __shared__ unsigned short Vs0[64*64];
    __shared__ unsigned short Vs1[64*64];

    const int t    = threadIdx.x;
    const int lane = t & 63;
    const int w    = t >> 6;
    const int l15  = lane & 15;
    const int quad = lane >> 4;

    const int bid   = blockIdx.x;         // 0..511
    const int xcd   = bid & 7;
    const int slot  = bid >> 3;           // 0..63
    const bool hv   = slot < 32;
    const int sub   = hv ? slot : slot - 32;
    const int bh    = xcd*4 + (sub >> 3);
    const int j     = sub & 7;
    const int QT    = hv ? 15 - j : j;
    const int n     = 2*QT + 2;           // k-tiles for this q-tile

    const int c0 = t,       r0 = c0 >> 3, g0 = ((c0 & 7) ^ (r0 & 7)) * 8;
    const int c1 = t + 256, r1 = c1 >> 3, g1 = ((c1 & 7) ^ (r1 & 7)) * 8;

    auto stage = [&](int skt, unsigned short* Ksb, unsigned short* Vsb) {
        const unsigned short* Kg = Ka + (size_t)bh * Ss * DKk + (size_t)skt*64*DKk;
        const unsigned short* Vg = Va + (size_t)bh * DKk * Ss + skt*64;
        gl16(Kg + (size_t)r0*DKk + g0, Ksb + t*8);
        gl16(Kg + (size_t)r1*DKk + g1, Ksb + (t+256)*8);
        gl16(Vg + (size_t)r0*Ss  + g0, Vsb + t*8);
        gl16(Vg + (size_t)r1*Ss  + g1, Vsb + (t+256)*8);
    };

    short8 qf[2][2];          // [mfq][kc]  B-frags of Q
    f32x4 o[2][4];            // [mfq][dt]  O C-frags
    float lacc[2];            // row-sum partial (this quad's keys)
    #pragma unroll
    for (int mfq = 0; mfq < 2; mfq++) {
        lacc[mfq] = 0.f;
        #pragma unroll
        for (int i = 0; i < 4; i++) o[mfq][i] = f32x4{0.f,0.f,0.f,0.f};
    }
    #pragma unroll
    for (int mfq = 0; mfq < 2; mfq++) {
        const unsigned short* qrow = Qa + (size_t)bh * Ss * DKk
            + (size_t)(QT*128 + w*32 + mfq*16 + l15) * DKk;
        qf[mfq][0] = *(const short8*)(qrow + quad*8);
        qf[mfq][1] = *(const short8*)(qrow + 32 + quad*8);
    }

    auto compute = [&](const unsigned short* Ksb, const unsigned short* Vsb,
                       int ckt) {
        // S^T = K Q^T : D[m=key nt*16+4quad+r][n=q w*32+mfq*16+l15]
        f32x4 sc[4][2];
        #pragma unroll
        for (int nt = 0; nt < 4; nt++)
            #pragma unroll
            for (int mfq = 0; mfq < 2; mfq++) sc[nt][mfq] = f32x4{0.f,0.f,0.f,0.f};
        #pragma unroll
        for (int nt = 0; nt < 4; nt++)
            #pragma unroll
            for (int kc = 0; kc < 2; kc++) {
                const short8 kf = *(const short8*)&Ksb[(nt*16 + l15)*64
                                   + (((kc*4 + quad) ^ (l15 & 7)) * 8)];
                sc[nt][0] = __builtin_amdgcn_mfma_f32_16x16x32_bf16(kf, qf[0][kc], sc[nt][0], 0,0,0);
                sc[nt][1] = __builtin_amdgcn_mfma_f32_16x16x32_bf16(kf, qf[1][kc], sc[nt][1], 0,0,0);
            }

        if (ckt >= 2*QT) {                      // diagonal tiles only
            const int kb = ckt*64 + quad*4;
            const int qb = QT*128 + w*32 + l15;
            #pragma unroll
            for (int nt = 0; nt < 4; nt++)
                #pragma unroll
                for (int mfq = 0; mfq < 2; mfq++)
                    #pragma unroll
                    for (int r = 0; r < 4; r++)
                        if (kb + nt*16 + r > qb + mfq*16)
                            sc[nt][mfq][r] = -INFINITY;
        }

        #pragma unroll
        for (int nt = 0; nt < 4; nt++)
            #pragma unroll
            for (int mfq = 0; mfq < 2; mfq++)
                #pragma unroll
                for (int r = 0; r < 4; r++)
                    sc[nt][mfq][r] = fexp2(sc[nt][mfq][r]);
        #pragma unroll
        for (int mfq = 0; mfq < 2; mfq++)
            #pragma unroll
            for (int nt = 0; nt < 4; nt++)
                lacc[mfq] += (sc[nt][mfq][0] + sc[nt][mfq][1])
                           + (sc[nt][mfq][2] + sc[nt][mfq][3]);

        // P A-frags via sigma: frag (mfq,kc) word v packs
        // sc[2kc+(v>>1)][mfq][2(v&1)] (lo), sc[2kc+(v>>1)][mfq][2(v&1)+1] (hi)
        short8 pfrag[2][2];                    // [mfq][kc]
        #pragma unroll
        for (int mfq = 0; mfq < 2; mfq++)
            #pragma unroll
            for (int kc = 0; kc < 2; kc++) {
                unsigned int pk[4];
                #pragma unroll
                for (int v = 0; v < 4; v++) {
                    const int nt = 2*kc + (v >> 1);
                    const int rr = 2*(v & 1);
                    pk[v] = cvtpk_bf16(sc[nt][mfq][rr], sc[nt][mfq][rr+1]);
                }
                pfrag[mfq][kc] = *(short8*)&pk[0];
            }

        // O += P V with sigma-permuted V B-frags (two b64 reads each)
        #pragma unroll
        for (int dt = 0; dt < 4; dt++) {
            const int row = dt*16 + l15;       // d row of Vt tile
            const int rx  = row & 7;
            const int wi  = 4*(quad & 1);
            #pragma unroll
            for (int kc = 0; kc < 2; kc++) {
                const ushort4 lo = *(const ushort4*)&Vsb[row*64
                                    + (((4*kc + (quad>>1)) ^ rx) * 8) + wi];
                const ushort4 hi = *(const ushort4*)&Vsb[row*64
                                    + (((4*kc + 2 + (quad>>1)) ^ rx) * 8) + wi];
                short8 vf;
                vf[0]=lo.x; vf[1]=lo.y; vf[2]=lo.z; vf[3]=lo.w;
                vf[4]=hi.x; vf[5]=hi.y; vf[6]=hi.z; vf[7]=hi.w;
                o[0][dt] = __builtin_amdgcn_mfma_f32_16x16x32_bf16(
                    pfrag[0][kc], vf, o[0][dt], 0,0,0);
                o[1][dt] = __builtin_amdgcn_mfma_f32_16x16x32_bf16(
                    pfrag[1][kc], vf, o[1][dt], 0,0,0);
            }
        }
    };

    stage(0, Ks0, Vs0);
    int i = 0;
    while (true) {
        __syncthreads();
        const bool h1 = (i + 1 < n);
        if (h1) stage(i + 1, Ks1, Vs1);
        compute(Ks0, Vs0, i);
        if (!h1) break;
        i++;
        __syncthreads();
        const bool h2 = (i + 1 < n);
        if (h2) stage(i + 1, Ks0, Vs0);
        compute(Ks1, Vs1, i);
        if (!h2) break;
        i++;
    }

    // Normalize and store bf16 (full key range was local to this block).
    {
        const int b = bh >> 4, h = bh & 15;
        const int q0 = QT*128 + w*32;
        #pragma unroll
        for (int mfq = 0; mfq < 2; mfq++) {
            float ls = lacc[mfq];
            ls += __shfl_xor(ls, 16);      // sum the 4 quads' key partials
            ls += __shfl_xor(ls, 32);      // -> every lane: denom for q-col l15
            #pragma unroll
            for (int r = 0; r < 4; r++) {
                const int x = quad*4 + r;  // q-row index within 16-block
                const float inv = 1.0f / __shfl(ls, (lane & 48) + x);
                const int row = q0 + mfq*16 + x;
                unsigned short* orow = Ob + ((size_t)b*Ss + row) * 1024 + h*64;
                #pragma unroll
                for (int dt = 0; dt < 4; dt++)
                    orow[dt*16 + l15] = f2bf(o[mfq][dt][r] * inv);
            }
        }
    }
}

// ---------------------------------------------------------------------------
extern "C" void kernel_launch(void* const* d_in, const int* in_sizes, int n_in,
                              void* d_out, int out_size, void* d_ws, size_t ws_size,
                              hipStream_t stream)
{
    const float* x    = (const float*)d_in[0];
    const float* Wqkv = (const float*)d_in[1];
    const float* Wo   = (const float*)d_in[2];
    float* out = (float*)d_out;
    unsigned short* wsu = (unsigned short*)d_ws;

    const dim3 blk(256);
    convert_bf16<<<dim3(8192), blk, 0, stream>>>(x, Wqkv, Wo, wsu);
    gemm_mfma<1,128><<<dim3(24, 32), blk, 0, stream>>>(wsu + XB_E, wsu + WQKV_E,
                                                       nullptr, wsu + QB_E, 3072);
    flash_mfma<<<dim3(512), blk, 0, stream>>>(wsu + QB_E, wsu + QB_E + QSZ,
                                              wsu + QB_E + 2*QSZ, wsu + OB_E);
    gemm_mfma<0,64><<<dim3(16, 32), blk, 0, stream>>>(wsu + OB_E, wsu + WOB_E,
                                                      out, nullptr, 1024);
}

// Round 14
// 167.718 us; speedup vs baseline: 1.0403x; 1.0183x over previous
//
#include <hip/hip_runtime.h>
#include <math.h>

// B=2, S=2048, D=1024, H=16, DK=64, rope_dim=32, causal MHA. fp32 in/out.
// convert->bf16 | QKV MFMA-GEMM dbuf (+fast RoPE; V^T via LDS transpose),
// XCD-chunked block swizzle (each XCD owns a 12x8 tile chunk -> L2-resident
// panels) | exclusive-ownership MFMA flash (r8: 512 blocks LPT-paired, zero
// atomics, in-kernel normalize) | out GEMM (8x8 XCD chunks). 4 dispatches.
// Locked flash config (r11 best): no setprio (r10), KVBLK=64 (r9),
// no launch_bounds forcing (r4).

static constexpr int Bb  = 2;
static constexpr int Ss  = 2048;
static constexpr int Hh  = 16;
static constexpr int DKk = 64;

static constexpr size_t QSZ = (size_t)Bb * Hh * Ss * DKk;   // 4,194,304

// ws bytes: Wo[0,2M) | x[2M,10M) | Wqkv[10M,16M) | Q[18M,26M) | K[26M,34M) |
//           Vt[34M,42M) | Ob[42M,50M).
static constexpr size_t WOB_E  = 0;
static constexpr size_t XB_E   = 1048576;
static constexpr size_t WQKV_E = 5242880;
static constexpr size_t QB_E   = 9437184;
static constexpr size_t OB_E   = QB_E + 3*QSZ;

typedef __attribute__((ext_vector_type(8))) short short8;
typedef __attribute__((ext_vector_type(4))) float f32x4;

__device__ __forceinline__ unsigned short f2bf(float f) {   // RNE
    unsigned int u = __float_as_uint(f);
    u += 0x7fffu + ((u >> 16) & 1u);
    return (unsigned short)(u >> 16);
}

// packed bf16x2 via HW cvt_pk (RNE): 1 VALU op vs 3+ for bit-munged pack.
__device__ __forceinline__ unsigned int cvtpk_bf16(float lo, float hi) {
    unsigned int r;
    asm("v_cvt_pk_bf16_f32 %0, %1, %2" : "=v"(r) : "v"(lo), "v"(hi));
    return r;
}

__device__ __forceinline__ float fexp2(float x) {           // 2^x, exp2(-inf)=0
    float r;
    asm("v_exp_f32 %0, %1" : "=v"(r) : "v"(x));
    return r;
}

__device__ __forceinline__ float fsin_rev(float r) {        // sin(2*pi*r)
    float o;
    asm("v_sin_f32 %0, %1" : "=v"(o) : "v"(r));
    return o;
}
__device__ __forceinline__ float fcos_rev(float r) {
    float o;
    asm("v_cos_f32 %0, %1" : "=v"(o) : "v"(r));
    return o;
}

__device__ __forceinline__ void gl16(const unsigned short* g, unsigned short* l) {
    __builtin_amdgcn_global_load_lds(
        (const __attribute__((address_space(1))) void*)g,
        (__attribute__((address_space(3))) void*)l, 16, 0, 0);
}

// ---------------------------------------------------------------------------
// fp32->bf16 of Wo | x | Wqkv into ws.
// ---------------------------------------------------------------------------
__global__ __launch_bounds__(256)
void convert_bf16(const float* __restrict__ x, const float* __restrict__ wqkv,
                  const float* __restrict__ wo, unsigned short* __restrict__ dst)
{
    const size_t i4 = ((size_t)blockIdx.x * 256 + threadIdx.x) * 4;
    const float* src;
    if (i4 < 1048576)      src = wo   + i4;
    else if (i4 < 5242880) src = x    + (i4 - 1048576);
    else                   src = wqkv + (i4 - 5242880);
    const float4 v = *(const float4*)src;
    ushort4 p = { f2bf(v.x), f2bf(v.y), f2bf(v.z), f2bf(v.w) };
    *(ushort4*)(dst + i4) = p;
}

// ---------------------------------------------------------------------------
// bf16 MFMA GEMM, dbuf in a flat LDS pool. C = A[M,K] * B[N,K]^T,
// K=1024, BK=32, BM=128, BN=128|64.  MODE 0: C fp32.  MODE 1: QKV scatter
// + fused RoPE (HW v_sin/v_cos); V^T written via per-wave LDS transpose
// (XOR-swizzled 4 KB chunk) as 128-B contiguous segments.
// GX = grid x-blocks. 1D launch of GX*32 blocks, XCD-chunked decode:
// xcd = bid&7 owns x in [(xcd&1)*GX/2, +GX/2) x y in [(xcd>>1)*8, +8)
// -> per-XCD L2 working set = (GX/2)*B-panel + 8*A-panel (~3-5 MB, near
// L2-resident) instead of all-B + all-A thrash. Latency-bound 2-phase loop:
// L2 hits (~200cy) hide under the compute phase where HBM misses don't.
// ---------------------------------------------------------------------------
template<int MODE, int BN, int GX>
__global__ __launch_bounds__(256)
void gemm_mfma(const unsigned short* __restrict__ A,
               const unsigned short* __restrict__ Bm,
               float* __restrict__ C, unsigned short* __restrict__ QKV, int N)
{
    constexpr int K   = 1024;
    constexpr int NF  = BN / 32;
    constexpr int ASZ = 128 * 32;
    constexpr int BSZ = BN * 32;
    __shared__ unsigned short ShPool[2 * ASZ + 2 * BSZ];
    unsigned short* As0 = ShPool;
    unsigned short* As1 = ShPool + ASZ;
    unsigned short* Bs0 = ShPool + 2 * ASZ;
    unsigned short* Bs1 = ShPool + 2 * ASZ + BSZ;

    const int t    = threadIdx.x;
    const int lane = t & 63;
    const int w    = t >> 6;
    const int l15  = lane & 15;
    const int quad = lane >> 4;
    const int wr   = w >> 1;
    const int wc   = w & 1;

    // XCD-chunked bijection: bid in [0, GX*32) -> (bx in [0,GX), by in [0,32))
    const int bid  = blockIdx.x;
    const int xcd  = bid & 7;
    const int idx  = bid >> 3;            // 0 .. GX*4-1
    constexpr int HX = GX / 2;
    const int bx   = (xcd & 1) * HX + idx % HX;
    const int by   = (xcd >> 1) * 8 + idx / HX;
    const int n0   = bx * BN;
    const int m0   = by * 128;

    const unsigned short* Ag = A  + (size_t)(m0 + (t >> 2)) * K + (t & 3) * 8;
    const unsigned short* Bg = Bm + (size_t)(n0 + (t >> 2)) * K + (t & 3) * 8;

    f32x4 acc[4][NF];
    #pragma unroll
    for (int i = 0; i < 4; i++)
        #pragma unroll
        for (int j = 0; j < NF; j++) acc[i][j] = f32x4{0.f, 0.f, 0.f, 0.f};

    auto stage = [&](int k0, unsigned short* Asb, unsigned short* Bsb) {
        gl16(Ag + k0,        Asb + t*8);
        gl16(Ag + 64*K + k0, Asb + 2048 + t*8);
        gl16(Bg + k0,        Bsb + t*8);
        if (BN == 128) gl16(Bg + 64*K + k0, Bsb + 2048 + t*8);
    };
    auto comp = [&](const unsigned short* Asb, const unsigned short* Bsb) {
        short8 af[4], bfv[NF];
        #pragma unroll
        for (int mf = 0; mf < 4; mf++)
            af[mf] = *(const short8*)&Asb[(wr*64 + mf*16 + l15) * 32 + quad*8];
        #pragma unroll
        for (int nf = 0; nf < NF; nf++)
            bfv[nf] = *(const short8*)&Bsb[(wc*(BN/2) + nf*16 + l15) * 32 + quad*8];
        #pragma unroll
        for (int mf = 0; mf < 4; mf++)
            #pragma unroll
            for (int nf = 0; nf < NF; nf++)
                acc[mf][nf] = __builtin_amdgcn_mfma_f32_16x16x32_bf16(
                    af[mf], bfv[nf], acc[mf][nf], 0, 0, 0);
    };

    stage(0, As0, Bs0);
    for (int k0 = 0; k0 < K; k0 += 64) {
        __syncthreads();
        stage(k0 + 32, As1, Bs1);
        comp(As0, Bs0);
        __syncthreads();
        if (k0 + 64 < K) stage(k0 + 64, As0, Bs0);
        comp(As1, Bs1);
    }

    if (MODE == 0) {
        #pragma unroll
        for (int mf = 0; mf < 4; mf++)
            #pragma unroll
            for (int r = 0; r < 4; r++) {
                float* crow = C + (size_t)(m0 + wr*64 + mf*16 + quad*4 + r) * N
                            + n0 + wc*(BN/2);
                #pragma unroll
                for (int nf = 0; nf < NF; nf++)
                    crow[nf*16 + l15] = acc[mf][nf][r];
            }
    } else {
        __syncthreads();                       // staging pool dead -> reusable
        const int col0 = n0 + wc*64;           // wave-uniform (BN=128)
        const int q    = col0 >> 10;
        const int h    = (col0 >> 6) & 15;
        const int row0 = m0 + wr*64;
        const int b    = row0 >> 11;
        const int s0   = row0 & 2047;
        if (q == 2) {
            // Wave holds the full 64x64 (s x d) V tile. Transpose via
            // wave-private 4 KB LDS chunk (byte ^= (d&7)<<4 swizzle) then
            // store Vt rows as 128-B contiguous segments.
            unsigned short* chunk = ShPool + w * 2048;     // 4 KB per wave
            unsigned short* vb = QKV + 2*QSZ
                               + (size_t)(b*Hh + h) * DKk * Ss + s0;
            #pragma unroll
            for (int pass = 0; pass < 2; pass++) {
                #pragma unroll
                for (int mf = 0; mf < 4; mf++)
                    #pragma unroll
                    for (int nfp = 0; nfp < 2; nfp++) {
                        const int nf = pass*2 + nfp;
                        const int dl = nfp*16 + l15;
                        const int sby = (mf*16 + quad*4) * 2;
                        ushort4 pv = { f2bf(acc[mf][nf][0]), f2bf(acc[mf][nf][1]),
                                       f2bf(acc[mf][nf][2]), f2bf(acc[mf][nf][3]) };
                        *(ushort4*)((char*)chunk
                            + dl*128 + (sby ^ ((dl & 7) << 4))) = pv;
                    }
                // same-wave LDS ops are in-order; no barrier needed
                #pragma unroll
                for (int dblk = 0; dblk < 8; dblk++) {
                    const int dl = dblk*4 + quad;          // 0..31
                    const int sl = l15*4;                  // s within tile
                    const ushort4 pv = *(const ushort4*)((char*)chunk
                        + dl*128 + ((sl*2) ^ ((dl & 7) << 4)));
                    *(ushort4*)(vb + (size_t)(pass*32 + dl) * Ss + sl) = pv;
                }
            }
        } else {
            // Q scale folds 1/sqrt(64) and log2(e) for flash's exp2 softmax
            const float qsc = (q == 0) ? 0.125f * 1.44269504088896f : 1.0f;
            const float rev_freq = (float)(exp(-(double)(2 * l15) / 32.0
                                   * log(6000.0)) / 6.283185307179586);
            unsigned short* base = QKV + (size_t)q * QSZ
                                 + ((size_t)(b*Hh + h) * Ss) * DKk;
            #pragma unroll
            for (int mf = 0; mf < 4; mf++)
                #pragma unroll
                for (int r = 0; r < 4; r++) {
                    const int s = s0 + mf*16 + quad*4 + r;
                    float rev = (float)s * rev_freq;
                    rev -= floorf(rev);
                    const float sn = fsin_rev(rev);
                    const float cs = fcos_rev(rev);
                    const float v0 = acc[mf][0][r] * qsc;
                    const float v1 = acc[mf][1][r] * qsc;
                    unsigned short* rowp = base + (size_t)s * DKk;
                    rowp[l15]      = f2bf(v0 * cs - v1 * sn);
                    rowp[16 + l15] = f2bf(v1 * cs + v0 * sn);
                    rowp[32 + l15] = f2bf(acc[mf][2][r] * qsc);
                    rowp[48 + l15] = f2bf(acc[mf][3][r] * qsc);
                }
        }
    }
}

// ---------------------------------------------------------------------------
// Exclusive-ownership MFMA causal flash, LPT-paired. 512 blocks, one q-tile
// (128 rows) each: xcd = bid&7 owns bh [4x,4x+4); slot = bid>>3 in [0,64):
// slots 0-31 heavy (QT = 15-(slot&7)), slots 32-63 light (QT = slot&7),
// same bh for slot s and s+32. Round-robin dispatch puts bid c and c+256 on
// the same CU -> every CU gets 34 items across 2 blocks (8 waves/CU), both
// streaming the same head's K/V. Zero atomics: full key range local ->
// normalize in-kernel, store bf16 Ob. 2-buffer LDS dbuf + __syncthreads.
// S computed TRANSPOSED (A=K, B=Q); sigma-permuted PV; cvt_pk P-pack.
// ---------------------------------------------------------------------------
__global__ __launch_bounds__(256)
void flash_mfma(const unsigned short* __restrict__ Qa,
                const unsigned short* __restrict__ Ka,
                const unsigned short* __restrict__ Va,
                unsigned short* __restrict__ Ob)
{
    __shared__ unsigned short Ks0[64*64];
    __shared__ unsigned short Ks1[64*64];
    __shared__ unsigned short Vs0[64*64];
    __shared__ unsigned short Vs1[64*64];

    const int t    = threadIdx.x;
    const int lane = t & 63;
    const int w    = t >> 6;
    const int l15  = lane & 15;
    const int quad = lane >> 4;

    const int bid   = blockIdx.x;         // 0..511
    const int xcd   = bid & 7;
    const int slot  = bid >> 3;           // 0..63
    const bool hv   = slot < 32;
    const int sub   = hv ? slot : slot - 32;
    const int bh    = xcd*4 + (sub >> 3);
    const int j     = sub & 7;
    const int QT    = hv ? 15 - j : j;
    const int n     = 2*QT + 2;           // k-tiles for this q-tile

    const int c0 = t,       r0 = c0 >> 3, g0 = ((c0 & 7) ^ (r0 & 7)) * 8;
    const int c1 = t + 256, r1 = c1 >> 3, g1 = ((c1 & 7) ^ (r1 & 7)) * 8;

    auto stage = [&](int skt, unsigned short* Ksb, unsigned short* Vsb) {
        const unsigned short* Kg = Ka + (size_t)bh * Ss * DKk + (size_t)skt*64*DKk;
        const unsigned short* Vg = Va + (size_t)bh * DKk * Ss + skt*64;
        gl16(Kg + (size_t)r0*DKk + g0, Ksb + t*8);
        gl16(Kg + (size_t)r1*DKk + g1, Ksb + (t+256)*8);
        gl16(Vg + (size_t)r0*Ss  + g0, Vsb + t*8);
        gl16(Vg + (size_t)r1*Ss  + g1, Vsb + (t+256)*8);
    };

    short8 qf[2][2];          // [mfq][kc]  B-frags of Q
    f32x4 o[2][4];            // [mfq][dt]  O C-frags
    float lacc[2];            // row-sum partial (this quad's keys)
    #pragma unroll
    for (int mfq = 0; mfq < 2; mfq++) {
        lacc[mfq] = 0.f;
        #pragma unroll
        for (int i = 0; i < 4; i++) o[mfq][i] = f32x4{0.f,0.f,0.f,0.f};
    }
    #pragma unroll
    for (int mfq = 0; mfq < 2; mfq++) {
        const unsigned short* qrow = Qa + (size_t)bh * Ss * DKk
            + (size_t)(QT*128 + w*32 + mfq*16 + l15) * DKk;
        qf[mfq][0] = *(const short8*)(qrow + quad*8);
        qf[mfq][1] = *(const short8*)(qrow + 32 + quad*8);
    }

    auto compute = [&](const unsigned short* Ksb, const unsigned short* Vsb,
                       int ckt) {
        // S^T = K Q^T : D[m=key nt*16+4quad+r][n=q w*32+mfq*16+l15]
        f32x4 sc[4][2];
        #pragma unroll
        for (int nt = 0; nt < 4; nt++)
            #pragma unroll
            for (int mfq = 0; mfq < 2; mfq++) sc[nt][mfq] = f32x4{0.f,0.f,0.f,0.f};
        #pragma unroll
        for (int nt = 0; nt < 4; nt++)
            #pragma unroll
            for (int kc = 0; kc < 2; kc++) {
                const short8 kf = *(const short8*)&Ksb[(nt*16 + l15)*64
                                   + (((kc*4 + quad) ^ (l15 & 7)) * 8)];
                sc[nt][0] = __builtin_amdgcn_mfma_f32_16x16x32_bf16(kf, qf[0][kc], sc[nt][0], 0,0,0);
                sc[nt][1] = __builtin_amdgcn_mfma_f32_16x16x32_bf16(kf, qf[1][kc], sc[nt][1], 0,0,0);
            }

        if (ckt >= 2*QT) {                      // diagonal tiles only
            const int kb = ckt*64 + quad*4;
            const int qb = QT*128 + w*32 + l15;
            #pragma unroll
            for (int nt = 0; nt < 4; nt++)
                #pragma unroll
                for (int mfq = 0; mfq < 2; mfq++)
                    #pragma unroll
                    for (int r = 0; r < 4; r++)
                        if (kb + nt*16 + r > qb + mfq*16)
                            sc[nt][mfq][r] = -INFINITY;
        }

        #pragma unroll
        for (int nt = 0; nt < 4; nt++)
            #pragma unroll
            for (int mfq = 0; mfq < 2; mfq++)
                #pragma unroll
                for (int r = 0; r < 4; r++)
                    sc[nt][mfq][r] = fexp2(sc[nt][mfq][r]);
        #pragma unroll
        for (int mfq = 0; mfq < 2; mfq++)
            #pragma unroll
            for (int nt = 0; nt < 4; nt++)
                lacc[mfq] += (sc[nt][mfq][0] + sc[nt][mfq][1])
                           + (sc[nt][mfq][2] + sc[nt][mfq][3]);

        // P A-frags via sigma: frag (mfq,kc) word v packs
        // sc[2kc+(v>>1)][mfq][2(v&1)] (lo), sc[2kc+(v>>1)][mfq][2(v&1)+1] (hi)
        short8 pfrag[2][2];                    // [mfq][kc]
        #pragma unroll
        for (int mfq = 0; mfq < 2; mfq++)
            #pragma unroll
            for (int kc = 0; kc < 2; kc++) {
                unsigned int pk[4];
                #pragma unroll
                for (int v = 0; v < 4; v++) {
                    const int nt = 2*kc + (v >> 1);
                    const int rr = 2*(v & 1);
                    pk[v] = cvtpk_bf16(sc[nt][mfq][rr], sc[nt][mfq][rr+1]);
                }
                pfrag[mfq][kc] = *(short8*)&pk[0];
            }

        // O += P V with sigma-permuted V B-frags (two b64 reads each)
        #pragma unroll
        for (int dt = 0; dt < 4; dt++) {
            const int row = dt*16 + l15;       // d row of Vt tile
            const int rx  = row & 7;
            const int wi  = 4*(quad & 1);
            #pragma unroll
            for (int kc = 0; kc < 2; kc++) {
                const ushort4 lo = *(const ushort4*)&Vsb[row*64
                                    + (((4*kc + (quad>>1)) ^ rx) * 8) + wi];
                const ushort4 hi = *(const ushort4*)&Vsb[row*64
                                    + (((4*kc + 2 + (quad>>1)) ^ rx) * 8) + wi];
                short8 vf;
                vf[0]=lo.x; vf[1]=lo.y; vf[2]=lo.z; vf[3]=lo.w;
                vf[4]=hi.x; vf[5]=hi.y; vf[6]=hi.z; vf[7]=hi.w;
                o[0][dt] = __builtin_amdgcn_mfma_f32_16x16x32_bf16(
                    pfrag[0][kc], vf, o[0][dt], 0,0,0);
                o[1][dt] = __builtin_amdgcn_mfma_f32_16x16x32_bf16(
                    pfrag[1][kc], vf, o[1][dt], 0,0,0);
            }
        }
    };

    stage(0, Ks0, Vs0);
    int i = 0;
    while (true) {
        __syncthreads();
        const bool h1 = (i + 1 < n);
        if (h1) stage(i + 1, Ks1, Vs1);
        compute(Ks0, Vs0, i);
        if (!h1) break;
        i++;
        __syncthreads();
        const bool h2 = (i + 1 < n);
        if (h2) stage(i + 1, Ks0, Vs0);
        compute(Ks1, Vs1, i);
        if (!h2) break;
        i++;
    }

    // Normalize and store bf16 (full key range was local to this block).
    {
        const int b = bh >> 4, h = bh & 15;
        const int q0 = QT*128 + w*32;
        #pragma unroll
        for (int mfq = 0; mfq < 2; mfq++) {
            float ls = lacc[mfq];
            ls += __shfl_xor(ls, 16);      // sum the 4 quads' key partials
            ls += __shfl_xor(ls, 32);      // -> every lane: denom for q-col l15
            #pragma unroll
            for (int r = 0; r < 4; r++) {
                const int x = quad*4 + r;  // q-row index within 16-block
                const float inv = 1.0f / __shfl(ls, (lane & 48) + x);
                const int row = q0 + mfq*16 + x;
                unsigned short* orow = Ob + ((size_t)b*Ss + row) * 1024 + h*64;
                #pragma unroll
                for (int dt = 0; dt < 4; dt++)
                    orow[dt*16 + l15] = f2bf(o[mfq][dt][r] * inv);
            }
        }
    }
}

// ---------------------------------------------------------------------------
extern "C" void kernel_launch(void* const* d_in, const int* in_sizes, int n_in,
                              void* d_out, int out_size, void* d_ws, size_t ws_size,
                              hipStream_t stream)
{
    const float* x    = (const float*)d_in[0];
    const float* Wqkv = (const float*)d_in[1];
    const float* Wo   = (const float*)d_in[2];
    float* out = (float*)d_out;
    unsigned short* wsu = (unsigned short*)d_ws;

    const dim3 blk(256);
    convert_bf16<<<dim3(8192), blk, 0, stream>>>(x, Wqkv, Wo, wsu);
    gemm_mfma<1,128,24><<<dim3(768), blk, 0, stream>>>(wsu + XB_E, wsu + WQKV_E,
                                                       nullptr, wsu + QB_E, 3072);
    flash_mfma<<<dim3(512), blk, 0, stream>>>(wsu + QB_E, wsu + QB_E + QSZ,
                                              wsu + QB_E + 2*QSZ, wsu + OB_E);
    gemm_mfma<0,64,16><<<dim3(512), blk, 0, stream>>>(wsu + OB_E, wsu + WOB_E,
                                                      out, nullptr, 1024);
}